// Round 5
// baseline (288.487 us; speedup 1.0000x reference)
//
#include <hip/hip_runtime.h>

// Problem constants
#define BATCH 4
#define SEQ   2048
#define DIM   1024
#define MTOT  (BATCH * SEQ)   // 8192
#define BK    32              // k-tile depth (m97-verified geometry)

typedef __bf16 bf16x8 __attribute__((ext_vector_type(8)));
typedef float  f32x4  __attribute__((ext_vector_type(4)));

// Async global->LDS, 16B per lane. LDS dest is wave-uniform base + lane*16;
// per-lane &lds[f*8] matches (lane order == contiguous LDS).
__device__ __forceinline__ void gl_lds16(const __bf16* g, __bf16* l) {
    __builtin_amdgcn_global_load_lds(
        (const __attribute__((address_space(1))) void*)g,
        (__attribute__((address_space(3))) void*)l,
        16, 0, 0);
}

// ---------------------------------------------------------------------------
// fp32 -> bf16 converts (inputs are fp32; compute in bf16 for MFMA).
__global__ __launch_bounds__(256) void cvt_kernel(
    const float* __restrict__ s, __bf16* __restrict__ d, int n)
{
    const int i = (blockIdx.x * 256 + threadIdx.x) * 8;
    if (i >= n) return;
    const float4 a = *(const float4*)(s + i);
    const float4 b = *(const float4*)(s + i + 4);
    bf16x8 o;
    o[0] = (__bf16)a.x; o[1] = (__bf16)a.y; o[2] = (__bf16)a.z; o[3] = (__bf16)a.w;
    o[4] = (__bf16)b.x; o[5] = (__bf16)b.y; o[6] = (__bf16)b.z; o[7] = (__bf16)b.w;
    *(bf16x8*)(d + i) = o;
}

__global__ __launch_bounds__(256) void cvt3_kernel(
    const float* __restrict__ w0, const float* __restrict__ w1,
    const float* __restrict__ w2, __bf16* __restrict__ d0,
    __bf16* __restrict__ d1, __bf16* __restrict__ d2)
{
    const int z = blockIdx.y;
    const float* s = (z == 0) ? w0 : (z == 1) ? w1 : w2;
    __bf16* d = (z == 0) ? d0 : (z == 1) ? d1 : d2;
    const int i = (blockIdx.x * 256 + threadIdx.x) * 8;
    const float4 a = *(const float4*)(s + i);
    const float4 b = *(const float4*)(s + i + 4);
    bf16x8 o;
    o[0] = (__bf16)a.x; o[1] = (__bf16)a.y; o[2] = (__bf16)a.z; o[3] = (__bf16)a.w;
    o[4] = (__bf16)b.x; o[5] = (__bf16)b.y; o[6] = (__bf16)b.z; o[7] = (__bf16)b.w;
    *(bf16x8*)(d + i) = o;
}

// ---------------------------------------------------------------------------
// 128x128 bf16 GEMM core (m97 structure), C[m,n] = sum_k A[m0+m,k]*B[n0+n,k],
// both row-major contiguous-K. BK=32, 256 threads = 4 waves 2x2, each wave
// 64x64 = 4x4 MFMA 16x16x32 tiles.
__device__ __forceinline__ void gemm_core(
    const __bf16* __restrict__ A, size_t lda,
    const __bf16* __restrict__ Bm, size_t ldb,
    int m0, int n0, int kTiles,
    __bf16* lA, __bf16* lB,
    f32x4 (&acc)[4][4])
{
    const int tid  = threadIdx.x;
    const int lane = tid & 63;
    const int wave = tid >> 6;
    const int wm = (wave >> 1) << 6;
    const int wn = (wave & 1) << 6;

#pragma unroll
    for (int i = 0; i < 4; ++i)
#pragma unroll
        for (int j = 0; j < 4; ++j)
            acc[i][j] = (f32x4){0.f, 0.f, 0.f, 0.f};

    for (int kt = 0; kt < kTiles; ++kt) {
        const int k0 = kt << 5;
        __syncthreads();
        // Stage A-tile [128][32] and B-tile [128][32], row-major, no pad.
#pragma unroll
        for (int it = 0; it < 2; ++it) {
            const int f   = tid + (it << 8);     // 8-elem group id, 0..511
            const int row = f >> 2;
            const int col = (f & 3) << 3;
            gl_lds16(A  + (size_t)(m0 + row) * lda + (size_t)(k0 + col), lA + f * 8);
            gl_lds16(Bm + (size_t)(n0 + row) * ldb + (size_t)(k0 + col), lB + f * 8);
        }
        __syncthreads();

        bf16x8 af[4], bfr[4];
#pragma unroll
        for (int i = 0; i < 4; ++i) {
            af[i]  = *(const bf16x8*)(lA + (size_t)(wm + i * 16 + (lane & 15)) * BK + ((lane >> 4) << 3));
            bfr[i] = *(const bf16x8*)(lB + (size_t)(wn + i * 16 + (lane & 15)) * BK + ((lane >> 4) << 3));
        }
#pragma unroll
        for (int i = 0; i < 4; ++i)
#pragma unroll
            for (int j = 0; j < 4; ++j)
                acc[i][j] = __builtin_amdgcn_mfma_f32_16x16x32_bf16(af[i], bfr[j], acc[i][j], 0, 0, 0);
    }
}

// Epilogue: C-tile -> LDS scratch -> coalesced bf16x8 row stores, in 4 passes
// of 32 rows so scratch (32 x 136 pad = 8.5 KB) fits the 16 KB staging LDS.
// Pad 136 (272 B row stride): 16B-aligned rows, transpose-write bank step 4
// -> 2-way conflict (free, m136).
__device__ __forceinline__ void store_tile_bf16(
    f32x4 (&acc)[4][4], __bf16* scratch, bool transpose, float scale,
    __bf16* dst, size_t ldo, size_t r0, size_t c0)
{
    const int tid  = threadIdx.x;
    const int lane = tid & 63;
    const int wave = tid >> 6;
    const int wm = (wave >> 1) << 6, wn = (wave & 1) << 6;
    const int quad = lane >> 4;
    const int ln15 = lane & 15;

#pragma unroll
    for (int p = 0; p < 4; ++p) {
        __syncthreads();            // scratch free (pass 0: staging now dead)
        if (!transpose) {
            // rows are m: waves with wm==(p>>1)*64, i in {2*(p&1), 2*(p&1)+1}
            if (wm == ((p >> 1) << 6)) {
#pragma unroll
                for (int ih = 0; ih < 2; ++ih) {
                    const int i = ((p & 1) << 1) + ih;
                    const int lr = ih * 16 + quad * 4;     // + r
#pragma unroll
                    for (int j = 0; j < 4; ++j)
#pragma unroll
                        for (int r = 0; r < 4; ++r)
                            scratch[(lr + r) * 136 + wn + j * 16 + ln15] =
                                (__bf16)(acc[i][j][r] * scale);
                }
            }
        } else {
            // rows are n: waves with wn==(p>>1)*64, j in {2*(p&1), 2*(p&1)+1}
            if (wn == ((p >> 1) << 6)) {
#pragma unroll
                for (int jh = 0; jh < 2; ++jh) {
                    const int j = ((p & 1) << 1) + jh;
                    const int lr = jh * 16 + ln15;
#pragma unroll
                    for (int i = 0; i < 4; ++i)
#pragma unroll
                        for (int r = 0; r < 4; ++r)
                            scratch[lr * 136 + wm + i * 16 + quad * 4 + r] =
                                (__bf16)(acc[i][j][r] * scale);
                }
            }
        }
        __syncthreads();
#pragma unroll
        for (int it = 0; it < 2; ++it) {
            const int g   = tid + (it << 8);   // 0..511
            const int row = g >> 4;            // 0..31
            const int col = (g & 15) << 3;
            *(bf16x8*)(dst + (r0 + p * 32 + row) * ldo + c0 + col) =
                *(const bf16x8*)(scratch + row * 136 + col);
        }
    }
}

// ---------------------------------------------------------------------------
// K1: Q = x@Wq^T, K = x@Wk^T, V = x@Wv^T (V stored transposed per batch:
// Vt[b][d][s]). grid = (24, 64): x-dim = n + 8*z so all (n,z) tiles of one
// m-row are dispatch-adjacent (L2/L3 locality for the x row-panel).
__global__ __launch_bounds__(256) void qkv_kernel(
    const __bf16* __restrict__ x,
    const __bf16* __restrict__ Wq,
    const __bf16* __restrict__ Wk,
    const __bf16* __restrict__ Wv,
    __bf16* __restrict__ Q, __bf16* __restrict__ Kb, __bf16* __restrict__ Vt)
{
    __shared__ __bf16 smem[8192];     // 16 KB: staging, then epilogue scratch
    __bf16* lA = smem;
    __bf16* lB = smem + 128 * BK;
    const int z  = blockIdx.x >> 3;
    const int n0 = (blockIdx.x & 7) << 7;
    const int m0 = blockIdx.y << 7;
    const __bf16* W = (z == 0) ? Wq : (z == 1) ? Wk : Wv;

    f32x4 acc[4][4];
    gemm_core(x, DIM, W, DIM, m0, n0, DIM / BK, lA, lB, acc);

    if (z == 0) {
        store_tile_bf16(acc, smem, false, 1.f, Q,  DIM, m0, n0);
    } else if (z == 1) {
        store_tile_bf16(acc, smem, false, 1.f, Kb, DIM, m0, n0);
    } else {
        // Vt[b][d][s]: rows = features (n), cols = seq (m) -> transpose.
        const size_t b = (size_t)(m0 >> 11), ms0 = (size_t)(m0 & (SEQ - 1));
        store_tile_bf16(acc, smem, true, 1.f, Vt + b * DIM * SEQ, SEQ, n0, ms0);
    }
}

// ---------------------------------------------------------------------------
// K2: Sc[b] = bf16( Q[b]·K[b]^T * (1/32) ), lower-triangle blocks. grid (16,16,4).
__global__ __launch_bounds__(256) void scores_kernel(
    const __bf16* __restrict__ Q, const __bf16* __restrict__ Kb,
    __bf16* __restrict__ Sc)
{
    const int j = blockIdx.x;   // kv block
    const int i = blockIdx.y;   // q block
    const int b = blockIdx.z;
    if (j > i) return;

    __shared__ __bf16 smem[8192];
    __bf16* lA = smem;
    __bf16* lB = smem + 128 * BK;
    const __bf16* A  = Q  + (size_t)b * SEQ * DIM;
    const __bf16* Bm = Kb + (size_t)b * SEQ * DIM;

    f32x4 acc[4][4];
    gemm_core(A, DIM, Bm, DIM, i << 7, j << 7, DIM / BK, lA, lB, acc);

    store_tile_bf16(acc, smem, false, 0.03125f,   // 1/sqrt(1024)
                    Sc + (size_t)b * SEQ * SEQ, SEQ, (size_t)(i << 7), (size_t)(j << 7));
}

// ---------------------------------------------------------------------------
// K3: causal row softmax on bf16 scores, in place. Zero-fills to the 128-tile
// boundary so PV diagonal tiles read valid zeros. grid = 8192 blocks of 256.
__global__ __launch_bounds__(256) void softmax_kernel(__bf16* __restrict__ Sc)
{
    const int rg = blockIdx.x;
    const int b  = rg >> 11;
    const int r  = rg & (SEQ - 1);
    __bf16* row = Sc + ((size_t)b * SEQ + r) * SEQ;

    const int tid  = threadIdx.x;
    const int lane = tid & 63;
    const int wv   = tid >> 6;
    const int width = ((r >> 7) + 1) << 7;   // tile-rounded valid width

    float v[8];
    float mx = -1e30f;
#pragma unroll
    for (int k = 0; k < 8; ++k) {
        const int c = tid + (k << 8);
        v[k] = (c <= r) ? (float)row[c] : -1e30f;
        mx = fmaxf(mx, v[k]);
    }
#pragma unroll
    for (int off = 32; off > 0; off >>= 1)
        mx = fmaxf(mx, __shfl_xor(mx, off));

    __shared__ float red[4];
    if (lane == 0) red[wv] = mx;
    __syncthreads();
    mx = fmaxf(fmaxf(red[0], red[1]), fmaxf(red[2], red[3]));

    float s = 0.f;
#pragma unroll
    for (int k = 0; k < 8; ++k) {
        const int c = tid + (k << 8);
        v[k] = (c <= r) ? __expf(v[k] - mx) : 0.f;
        s += v[k];
    }
#pragma unroll
    for (int off = 32; off > 0; off >>= 1)
        s += __shfl_xor(s, off);
    __syncthreads();             // red reuse
    if (lane == 0) red[wv] = s;
    __syncthreads();
    s = red[0] + red[1] + red[2] + red[3];
    const float inv = 1.f / s;

#pragma unroll
    for (int k = 0; k < 8; ++k) {
        const int c = tid + (k << 8);
        if (c < width) row[c] = (__bf16)(v[k] * inv);
    }
}

// ---------------------------------------------------------------------------
// K4: O[b] = P[b] @ V[b]  (A = P bf16 in Sc, lda = SEQ; B = Vt). k-tiles only
// up to the causal diagonal. Output fp32 (reference dtype). grid (8,16,4).
__global__ __launch_bounds__(256) void pv_kernel(
    const __bf16* __restrict__ P, const __bf16* __restrict__ Vt,
    float* __restrict__ out)
{
    const int x = blockIdx.x;   // feature block
    const int i = blockIdx.y;   // q block
    const int b = blockIdx.z;

    __shared__ __bf16 smem[8192];
    __bf16* lA = smem;
    __bf16* lB = smem + 128 * BK;
    const __bf16* A  = P  + (size_t)b * SEQ * SEQ;
    const __bf16* Bm = Vt + (size_t)b * DIM * SEQ;

    f32x4 acc[4][4];
    gemm_core(A, SEQ, Bm, SEQ, i << 7, x << 7, (i + 1) * (128 / BK), lA, lB, acc);

    const int lane = threadIdx.x & 63;
    const int wave = threadIdx.x >> 6;
    const int wm = (wave >> 1) << 6, wn = (wave & 1) << 6;
#pragma unroll
    for (int ii = 0; ii < 4; ++ii)
#pragma unroll
        for (int jj = 0; jj < 4; ++jj)
#pragma unroll
            for (int r = 0; r < 4; ++r) {
                const int m = (i << 7) + wm + ii * 16 + ((lane >> 4) << 2) + r;
                const int n = (x << 7) + wn + jj * 16 + (lane & 15);
                out[((size_t)b * SEQ + m) * DIM + n] = acc[ii][jj][r];
            }
}

// ---------------------------------------------------------------------------
extern "C" void kernel_launch(void* const* d_in, const int* in_sizes, int n_in,
                              void* d_out, int out_size, void* d_ws, size_t ws_size,
                              hipStream_t stream) {
    const float* x  = (const float*)d_in[0];   // fp32 per reference
    const float* Wq = (const float*)d_in[1];
    const float* Wk = (const float*)d_in[2];
    const float* Wv = (const float*)d_in[3];
    float* out = (float*)d_out;                // fp32 output (reference dtype)

    char* ws = (char*)d_ws;
    __bf16* Q  = (__bf16*)(ws);                       // 16 MB
    __bf16* Kb = (__bf16*)(ws + (16ull << 20));       // 16 MB
    __bf16* Vt = (__bf16*)(ws + (32ull << 20));       // 16 MB
    __bf16* Sc = (__bf16*)(ws + (48ull << 20));       // 32 MB bf16 scores/P
    // bf16 input copies alias the Sc region head: dead after qkv_kernel,
    // Sc first written by scores_kernel (later).
    __bf16* xb  = (__bf16*)(ws + (48ull << 20));      // 16 MB (aliases Sc)
    __bf16* Wqb = (__bf16*)(ws + (80ull << 20));      // 2 MB
    __bf16* Wkb = (__bf16*)(ws + (82ull << 20));      // 2 MB
    __bf16* Wvb = (__bf16*)(ws + (84ull << 20));      // 2 MB

    const int nx = BATCH * SEQ * DIM;   // 8388608
    const int nw = DIM * DIM;           // 1048576
    cvt_kernel <<<dim3(nx / (256 * 8)),    256, 0, stream>>>(x, xb, nx);
    cvt3_kernel<<<dim3(nw / (256 * 8), 3), 256, 0, stream>>>(Wq, Wk, Wv, Wqb, Wkb, Wvb);

    qkv_kernel    <<<dim3(24, 64),    256, 0, stream>>>(xb, Wqb, Wkb, Wvb, Q, Kb, Vt);
    scores_kernel <<<dim3(16, 16, 4), 256, 0, stream>>>(Q, Kb, Sc);
    softmax_kernel<<<dim3(MTOT),      256, 0, stream>>>(Sc);
    pv_kernel     <<<dim3(8, 16, 4),  256, 0, stream>>>(Sc, Vt, out);
}

// Round 6
// 262.909 us; speedup vs baseline: 1.0973x; 1.0973x over previous
//
#include <hip/hip_runtime.h>

// Problem constants
#define BATCH 4
#define SEQ   2048
#define DIM   1024
#define MTOT  (BATCH * SEQ)   // 8192
#define BK    32              // k-tile depth (m97-verified geometry)

typedef __bf16 bf16x8 __attribute__((ext_vector_type(8)));
typedef float  f32x4  __attribute__((ext_vector_type(4)));

// Async global->LDS, 16B per lane. LDS dest is wave-uniform base + lane*16;
// per-lane &lds[f*8] matches (lane order == contiguous LDS).
__device__ __forceinline__ void gl_lds16(const __bf16* g, __bf16* l) {
    __builtin_amdgcn_global_load_lds(
        (const __attribute__((address_space(1))) void*)g,
        (__attribute__((address_space(3))) void*)l,
        16, 0, 0);
}

// ---------------------------------------------------------------------------
// K0: fused fp32 -> bf16 conversion for x, Wq, Wk, Wv in ONE launch.
// Blocks [0,4096): x (8M elems). Blocks [4096,4608): Wq, then Wk, Wv.
__global__ __launch_bounds__(256) void cvt_all_kernel(
    const float* __restrict__ x,  const float* __restrict__ w0,
    const float* __restrict__ w1, const float* __restrict__ w2,
    __bf16* __restrict__ xd, __bf16* __restrict__ d0,
    __bf16* __restrict__ d1, __bf16* __restrict__ d2)
{
    const int bid = blockIdx.x;
    const float* s;
    __bf16* d;
    int base;
    if (bid < 4096)      { s = x;  d = xd; base = bid; }
    else if (bid < 4608) { s = w0; d = d0; base = bid - 4096; }
    else if (bid < 5120) { s = w1; d = d1; base = bid - 4608; }
    else                 { s = w2; d = d2; base = bid - 5120; }
    const int i = (base * 256 + threadIdx.x) * 8;
    const float4 a = *(const float4*)(s + i);
    const float4 b = *(const float4*)(s + i + 4);
    bf16x8 o;
    o[0] = (__bf16)a.x; o[1] = (__bf16)a.y; o[2] = (__bf16)a.z; o[3] = (__bf16)a.w;
    o[4] = (__bf16)b.x; o[5] = (__bf16)b.y; o[6] = (__bf16)b.z; o[7] = (__bf16)b.w;
    *(bf16x8*)(d + i) = o;
}

// ---------------------------------------------------------------------------
// 128x128 bf16 GEMM core (m97 structure), C[m,n] = sum_k A[m0+m,k]*B[n0+n,k],
// both row-major contiguous-K. BK=32, 256 threads = 4 waves 2x2, each wave
// 64x64 = 4x4 MFMA 16x16x32 tiles.
__device__ __forceinline__ void gemm_core(
    const __bf16* __restrict__ A, size_t lda,
    const __bf16* __restrict__ Bm, size_t ldb,
    int m0, int n0, int kTiles,
    __bf16* lA, __bf16* lB,
    f32x4 (&acc)[4][4])
{
    const int tid  = threadIdx.x;
    const int lane = tid & 63;
    const int wave = tid >> 6;
    const int wm = (wave >> 1) << 6;
    const int wn = (wave & 1) << 6;

#pragma unroll
    for (int i = 0; i < 4; ++i)
#pragma unroll
        for (int j = 0; j < 4; ++j)
            acc[i][j] = (f32x4){0.f, 0.f, 0.f, 0.f};

    for (int kt = 0; kt < kTiles; ++kt) {
        const int k0 = kt << 5;
        __syncthreads();
        // Stage A-tile [128][32] and B-tile [128][32], row-major, no pad.
#pragma unroll
        for (int it = 0; it < 2; ++it) {
            const int f   = tid + (it << 8);     // 8-elem group id, 0..511
            const int row = f >> 2;
            const int col = (f & 3) << 3;
            gl_lds16(A  + (size_t)(m0 + row) * lda + (size_t)(k0 + col), lA + f * 8);
            gl_lds16(Bm + (size_t)(n0 + row) * ldb + (size_t)(k0 + col), lB + f * 8);
        }
        __syncthreads();

        bf16x8 af[4], bfr[4];
#pragma unroll
        for (int i = 0; i < 4; ++i) {
            af[i]  = *(const bf16x8*)(lA + (size_t)(wm + i * 16 + (lane & 15)) * BK + ((lane >> 4) << 3));
            bfr[i] = *(const bf16x8*)(lB + (size_t)(wn + i * 16 + (lane & 15)) * BK + ((lane >> 4) << 3));
        }
#pragma unroll
        for (int i = 0; i < 4; ++i)
#pragma unroll
            for (int j = 0; j < 4; ++j)
                acc[i][j] = __builtin_amdgcn_mfma_f32_16x16x32_bf16(af[i], bfr[j], acc[i][j], 0, 0, 0);
    }
}

// Epilogue: C-tile -> LDS scratch -> coalesced bf16x8 row stores, in 4 passes
// of 32 rows so scratch (32 x 136 pad = 8.5 KB) fits the 16 KB staging LDS.
__device__ __forceinline__ void store_tile_bf16(
    f32x4 (&acc)[4][4], __bf16* scratch, bool transpose, float scale,
    __bf16* dst, size_t ldo, size_t r0, size_t c0)
{
    const int tid  = threadIdx.x;
    const int lane = tid & 63;
    const int wave = tid >> 6;
    const int wm = (wave >> 1) << 6, wn = (wave & 1) << 6;
    const int quad = lane >> 4;
    const int ln15 = lane & 15;

#pragma unroll
    for (int p = 0; p < 4; ++p) {
        __syncthreads();            // scratch free (pass 0: staging now dead)
        if (!transpose) {
            if (wm == ((p >> 1) << 6)) {
#pragma unroll
                for (int ih = 0; ih < 2; ++ih) {
                    const int i = ((p & 1) << 1) + ih;
                    const int lr = ih * 16 + quad * 4;
#pragma unroll
                    for (int j = 0; j < 4; ++j)
#pragma unroll
                        for (int r = 0; r < 4; ++r)
                            scratch[(lr + r) * 136 + wn + j * 16 + ln15] =
                                (__bf16)(acc[i][j][r] * scale);
                }
            }
        } else {
            if (wn == ((p >> 1) << 6)) {
#pragma unroll
                for (int jh = 0; jh < 2; ++jh) {
                    const int j = ((p & 1) << 1) + jh;
                    const int lr = jh * 16 + ln15;
#pragma unroll
                    for (int i = 0; i < 4; ++i)
#pragma unroll
                        for (int r = 0; r < 4; ++r)
                            scratch[lr * 136 + wm + i * 16 + quad * 4 + r] =
                                (__bf16)(acc[i][j][r] * scale);
                }
            }
        }
        __syncthreads();
#pragma unroll
        for (int it = 0; it < 2; ++it) {
            const int g   = tid + (it << 8);   // 0..511
            const int row = g >> 4;            // 0..31
            const int col = (g & 15) << 3;
            *(bf16x8*)(dst + (r0 + p * 32 + row) * ldo + c0 + col) =
                *(const bf16x8*)(scratch + row * 136 + col);
        }
    }
}

// ---------------------------------------------------------------------------
// K1: Q = x@Wq^T, K = x@Wk^T, V = x@Wv^T (V stored transposed per batch:
// Vt[b][d][s]). grid = (24, 64): x-dim = n + 8*z so all (n,z) tiles of one
// m-row are dispatch-adjacent (L2/L3 locality for the x row-panel).
__global__ __launch_bounds__(256) void qkv_kernel(
    const __bf16* __restrict__ x,
    const __bf16* __restrict__ Wq,
    const __bf16* __restrict__ Wk,
    const __bf16* __restrict__ Wv,
    __bf16* __restrict__ Q, __bf16* __restrict__ Kb, __bf16* __restrict__ Vt)
{
    __shared__ __bf16 smem[8192];     // 16 KB: staging, then epilogue scratch
    __bf16* lA = smem;
    __bf16* lB = smem + 128 * BK;
    const int z  = blockIdx.x >> 3;
    const int n0 = (blockIdx.x & 7) << 7;
    const int m0 = blockIdx.y << 7;
    const __bf16* W = (z == 0) ? Wq : (z == 1) ? Wk : Wv;

    f32x4 acc[4][4];
    gemm_core(x, DIM, W, DIM, m0, n0, DIM / BK, lA, lB, acc);

    if (z == 0) {
        store_tile_bf16(acc, smem, false, 1.f, Q,  DIM, m0, n0);
    } else if (z == 1) {
        store_tile_bf16(acc, smem, false, 1.f, Kb, DIM, m0, n0);
    } else {
        const size_t b = (size_t)(m0 >> 11), ms0 = (size_t)(m0 & (SEQ - 1));
        store_tile_bf16(acc, smem, true, 1.f, Vt + b * DIM * SEQ, SEQ, n0, ms0);
    }
}

// ---------------------------------------------------------------------------
// K2: Sc[b] = bf16( Q[b]·K[b]^T * (1/32) ), tri-packed grid: 544 blocks, no
// dead blocks. id -> (b, t), t -> (i,j) lower-triangle decode.
__global__ __launch_bounds__(256) void scores_kernel(
    const __bf16* __restrict__ Q, const __bf16* __restrict__ Kb,
    __bf16* __restrict__ Sc)
{
    const int id = blockIdx.x;
    const int b  = id / 136;
    const int t  = id - b * 136;
    int i = (int)((sqrtf(8.f * t + 1.f) - 1.f) * 0.5f);
    while ((i + 1) * (i + 2) / 2 <= t) ++i;
    while (i * (i + 1) / 2 > t) --i;
    const int j = t - i * (i + 1) / 2;

    __shared__ __bf16 smem[8192];
    __bf16* lA = smem;
    __bf16* lB = smem + 128 * BK;
    const __bf16* A  = Q  + (size_t)b * SEQ * DIM;
    const __bf16* Bm = Kb + (size_t)b * SEQ * DIM;

    f32x4 acc[4][4];
    gemm_core(A, DIM, Bm, DIM, i << 7, j << 7, DIM / BK, lA, lB, acc);

    store_tile_bf16(acc, smem, false, 0.03125f,   // 1/sqrt(1024)
                    Sc + (size_t)b * SEQ * SEQ, SEQ, (size_t)(i << 7), (size_t)(j << 7));
}

// ---------------------------------------------------------------------------
// K3: causal row softmax on bf16 scores, in place, vectorized bf16x8.
// Zero-fills to the 128-tile boundary. grid = 8192 blocks of 256.
__global__ __launch_bounds__(256) void softmax_kernel(__bf16* __restrict__ Sc)
{
    const int rg = blockIdx.x;
    const int b  = rg >> 11;
    const int r  = rg & (SEQ - 1);
    __bf16* row = Sc + ((size_t)b * SEQ + r) * SEQ;

    const int tid  = threadIdx.x;
    const int lane = tid & 63;
    const int wv   = tid >> 6;
    const int width = ((r >> 7) + 1) << 7;   // tile-rounded valid width
    const int c0 = tid << 3;                 // 8 contiguous elems per thread

    float v[8];
    float mx = -1e30f;
    if (c0 < width) {
        const bf16x8 in = *(const bf16x8*)(row + c0);
#pragma unroll
        for (int k = 0; k < 8; ++k) {
            v[k] = (c0 + k <= r) ? (float)in[k] : -1e30f;
            mx = fmaxf(mx, v[k]);
        }
    } else {
#pragma unroll
        for (int k = 0; k < 8; ++k) v[k] = -1e30f;
    }
#pragma unroll
    for (int off = 32; off > 0; off >>= 1)
        mx = fmaxf(mx, __shfl_xor(mx, off));

    __shared__ float red[4];
    if (lane == 0) red[wv] = mx;
    __syncthreads();
    mx = fmaxf(fmaxf(red[0], red[1]), fmaxf(red[2], red[3]));

    float s = 0.f;
#pragma unroll
    for (int k = 0; k < 8; ++k) {
        v[k] = (v[k] > -1e29f) ? __expf(v[k] - mx) : 0.f;
        s += v[k];
    }
#pragma unroll
    for (int off = 32; off > 0; off >>= 1)
        s += __shfl_xor(s, off);
    __syncthreads();             // red reuse
    if (lane == 0) red[wv] = s;
    __syncthreads();
    s = red[0] + red[1] + red[2] + red[3];
    const float inv = 1.f / s;

    if (c0 < width) {
        bf16x8 o;
#pragma unroll
        for (int k = 0; k < 8; ++k) o[k] = (__bf16)(v[k] * inv);
        *(bf16x8*)(row + c0) = o;
    }
}

// ---------------------------------------------------------------------------
// K4: O[b] = P[b] @ V[b]  (A = P bf16 in Sc, lda = SEQ; B = Vt). k-tiles only
// up to the causal diagonal. 1-D grid of 512, decoded i-DESCENDING so the
// longest blocks (i=15: 64 k-iters) dispatch first (LPT scheduling).
__global__ __launch_bounds__(256) void pv_kernel(
    const __bf16* __restrict__ P, const __bf16* __restrict__ Vt,
    float* __restrict__ out)
{
    const int id = blockIdx.x;
    const int i  = 15 - (id >> 5);        // q block, heavy first
    const int x  = id & 7;                // feature block
    const int b  = (id >> 3) & 3;         // batch

    __shared__ __bf16 smem[8192];
    __bf16* lA = smem;
    __bf16* lB = smem + 128 * BK;
    const __bf16* A  = P  + (size_t)b * SEQ * SEQ;
    const __bf16* Bm = Vt + (size_t)b * DIM * SEQ;

    f32x4 acc[4][4];
    gemm_core(A, SEQ, Bm, SEQ, i << 7, x << 7, (i + 1) * (128 / BK), lA, lB, acc);

    const int lane = threadIdx.x & 63;
    const int wave = threadIdx.x >> 6;
    const int wm = (wave >> 1) << 6, wn = (wave & 1) << 6;
#pragma unroll
    for (int ii = 0; ii < 4; ++ii)
#pragma unroll
        for (int jj = 0; jj < 4; ++jj)
#pragma unroll
            for (int r = 0; r < 4; ++r) {
                const int m = (i << 7) + wm + ii * 16 + ((lane >> 4) << 2) + r;
                const int n = (x << 7) + wn + jj * 16 + (lane & 15);
                out[((size_t)b * SEQ + m) * DIM + n] = acc[ii][jj][r];
            }
}

// ---------------------------------------------------------------------------
extern "C" void kernel_launch(void* const* d_in, const int* in_sizes, int n_in,
                              void* d_out, int out_size, void* d_ws, size_t ws_size,
                              hipStream_t stream) {
    const float* x  = (const float*)d_in[0];   // fp32 per reference
    const float* Wq = (const float*)d_in[1];
    const float* Wk = (const float*)d_in[2];
    const float* Wv = (const float*)d_in[3];
    float* out = (float*)d_out;                // fp32 output (reference dtype)

    char* ws = (char*)d_ws;
    __bf16* Q  = (__bf16*)(ws);                       // 16 MB
    __bf16* Kb = (__bf16*)(ws + (16ull << 20));       // 16 MB
    __bf16* Vt = (__bf16*)(ws + (32ull << 20));       // 16 MB
    __bf16* Sc = (__bf16*)(ws + (48ull << 20));       // 32 MB bf16 scores/P
    // bf16 input copies alias the Sc region head: dead after qkv_kernel,
    // Sc first written by scores_kernel (later).
    __bf16* xb  = (__bf16*)(ws + (48ull << 20));      // 16 MB (aliases Sc)
    __bf16* Wqb = (__bf16*)(ws + (80ull << 20));      // 2 MB
    __bf16* Wkb = (__bf16*)(ws + (82ull << 20));      // 2 MB
    __bf16* Wvb = (__bf16*)(ws + (84ull << 20));      // 2 MB

    cvt_all_kernel<<<dim3(5632), 256, 0, stream>>>(x, Wq, Wk, Wv, xb, Wqb, Wkb, Wvb);

    qkv_kernel    <<<dim3(24, 64), 256, 0, stream>>>(xb, Wqb, Wkb, Wvb, Q, Kb, Vt);
    scores_kernel <<<dim3(544),    256, 0, stream>>>(Q, Kb, Sc);
    softmax_kernel<<<dim3(MTOT),   256, 0, stream>>>(Sc);
    pv_kernel     <<<dim3(512),    256, 0, stream>>>(Sc, Vt, out);
}